// Round 2
// baseline (514.848 us; speedup 1.0000x reference)
//
#include <hip/hip_runtime.h>
#include <math.h>

#define B_   4096
#define N_   64
#define HID_ 256
#define NH_  8
#define HD_  32
#define INV_SQRT_HD 0.17677669529663687f

typedef const float __attribute__((address_space(1)))* gbl_fp;
typedef float __attribute__((address_space(3)))* lds_fp;

// ============================ Kernel 1 ======================================
// 512 blocks x 256 threads; block handles 8 rows of h_recv.
// Outputs: qh_ws[B][8][256], b1_ws[B][8], konst_ws[B][8] (pre-scaled)
__global__ __launch_bounds__(256, 2) void k1_proj(
    const float* __restrict__ h_recv,
    const float* __restrict__ wq_w, const float* __restrict__ wq_b,
    const float* __restrict__ wk_w, const float* __restrict__ wk_b,
    const float* __restrict__ d1_w, const float* __restrict__ d1_b,
    const float* __restrict__ d2_w, const float* __restrict__ d2_b,
    float* __restrict__ qh_ws, float* __restrict__ b1_ws, float* __restrict__ konst_ws)
{
    __shared__ __align__(16) float hr[8][256];
    __shared__ __align__(16) float Q[8][256];
    __shared__ float R1[8][128];
    const int t = threadIdx.x;
    const int brow = blockIdx.x * 8;

    {
        const float4* src = (const float4*)(h_recv + (size_t)brow * 256);
        float4* dst = (float4*)&hr[0][0];
        dst[t] = src[t];
        dst[t + 256] = src[t + 256];
    }
    __syncthreads();

    // Phase A: Q[bb][j], j = t
    {
        const int j = t;
        float acc[8];
        const float bq = wq_b[j];
#pragma unroll
        for (int bb = 0; bb < 8; bb++) acc[bb] = bq;
        for (int c4 = 0; c4 < 64; c4++) {
            const float w0 = wq_w[(c4 * 4 + 0) * 256 + j];
            const float w1 = wq_w[(c4 * 4 + 1) * 256 + j];
            const float w2 = wq_w[(c4 * 4 + 2) * 256 + j];
            const float w3 = wq_w[(c4 * 4 + 3) * 256 + j];
#pragma unroll
            for (int bb = 0; bb < 8; bb++) {
                const float4 h = *(const float4*)&hr[bb][c4 * 4];
                acc[bb] += h.x * w0 + h.y * w1 + h.z * w2 + h.w * w3;
            }
        }
#pragma unroll
        for (int bb = 0; bb < 8; bb++) Q[bb][j] = acc[bb];
    }
    __syncthreads();

    // Phase B: R1 = relu(h_recv @ d1 + d1_b)
    {
        const int j = t & 127;
        const int bg = t >> 7;
        float acc[4];
        const float bd = d1_b[j];
#pragma unroll
        for (int r = 0; r < 4; r++) acc[r] = bd;
        for (int c4 = 0; c4 < 64; c4++) {
            const float w0 = d1_w[(c4 * 4 + 0) * 128 + j];
            const float w1 = d1_w[(c4 * 4 + 1) * 128 + j];
            const float w2 = d1_w[(c4 * 4 + 2) * 128 + j];
            const float w3 = d1_w[(c4 * 4 + 3) * 128 + j];
#pragma unroll
            for (int r = 0; r < 4; r++) {
                const float4 h = *(const float4*)&hr[bg * 4 + r][c4 * 4];
                acc[r] += h.x * w0 + h.y * w1 + h.z * w2 + h.w * w3;
            }
        }
#pragma unroll
        for (int r = 0; r < 4; r++) R1[bg * 4 + r][j] = fmaxf(acc[r], 0.0f);
    }
    __syncthreads();

    // Phase C (t<64): softplus MLP head + pre-scaled wk_b constant
    if (t < 64) {
        const int bb = t >> 3, h = t & 7;
        float acc = d2_b[h];
        for (int jj = 0; jj < 128; jj++) acc += R1[bb][jj] * d2_w[jj * 8 + h];
        const float sp = (acc > 20.0f) ? acc : log1pf(expf(acc));
        b1_ws[(size_t)(brow + bb) * 8 + h] = sp;
        float k = 0.0f;
        for (int d = 0; d < 32; d++) k += Q[bb][h * 32 + d] * wk_b[h * 32 + d];
        konst_ws[(size_t)(brow + bb) * 8 + h] = k * INV_SQRT_HD;
    }

    // Phase D: qh[bb][h][c] = sum_d Q[bb][h*32+d] * wk[c][h*32+d]; c = t
    {
        const int c = t;
        for (int h = 0; h < 8; h++) {
            float acc[8] = {0, 0, 0, 0, 0, 0, 0, 0};
#pragma unroll
            for (int d4 = 0; d4 < 8; d4++) {
                const float4 w = *(const float4*)&wk_w[(size_t)c * 256 + h * 32 + d4 * 4];
#pragma unroll
                for (int bb = 0; bb < 8; bb++) {
                    const float4 q = *(const float4*)&Q[bb][h * 32 + d4 * 4];
                    acc[bb] += q.x * w.x + q.y * w.y + q.z * w.z + q.w * w.w;
                }
            }
#pragma unroll
            for (int bb = 0; bb < 8; bb++)
                qh_ws[((size_t)(brow + bb) * 8 + h) * 256 + c] = acc[bb];
        }
    }
}

// ============================ Kernel 2 (fused attn + z) =====================
// One block (256 thr) per batch element. LDS ~77.9 KB -> 2 blocks/CU.
__global__ __launch_bounds__(256, 2) void k2_attn(
    const float* __restrict__ h_send,
    const float* __restrict__ dist, const int* __restrict__ mask,
    const float* __restrict__ qh_ws, const float* __restrict__ b1_ws,
    const float* __restrict__ konst_ws,
    const float* __restrict__ wv_w, const float* __restrict__ wv_b,
    float* __restrict__ z_out,             // [B][256]
    float* __restrict__ attn_out)          // [B][64][8]
{
    __shared__ __align__(16) float hs[64][260];     // 66.5 KB, pad keeps row banks spread
    __shared__ __align__(16) float qh2[8][4][68];   // quarter-padded -> disjoint bank quads
    __shared__ __align__(16) float sc4[64][8];      // [n][h], contiguous == attn layout
    __shared__ float dist_l[64];
    __shared__ float b1_l[8], kon_l[8];
    __shared__ int mask_l[64];

    const int t = threadIdx.x;
    const int b = blockIdx.x;
    const int w = t >> 6;
    const int l = t & 63;

    // ---- async stage h_send[b] (64KB) via global_load_lds; wave w owns row i*4+w
    {
        const float* src = h_send + (size_t)b * 16384;
#pragma unroll
        for (int i = 0; i < 16; i++) {
            const int row = i * 4 + w;                       // wave-uniform
            __builtin_amdgcn_global_load_lds((gbl_fp)(src + row * 256 + l * 4),
                                             (lds_fp)&hs[row][0], 16, 0, 0);
        }
    }
    // ---- qh stage into quarter-padded layout + small vectors ----
    {
        const float4* qsrc = (const float4*)(qh_ws + (size_t)b * 2048);
#pragma unroll
        for (int k = 0; k < 2; k++) {
            const int e = t + k * 256;                       // float4 index in [8][256]
            const float4 v = qsrc[e];
            const int h = e >> 6;
            const int qq = (e & 63) >> 4;
            const int pos = (e & 15) * 4;
            *(float4*)&qh2[h][qq][pos] = v;
        }
        if (t < 64) {
            dist_l[t] = dist[(size_t)b * 64 + t];
            mask_l[t] = mask[(size_t)b * 64 + t];
        } else if (t < 72) {
            b1_l[t - 64] = b1_ws[(size_t)b * 8 + (t - 64)];
            kon_l[t - 64] = konst_ws[(size_t)b * 8 + (t - 64)];
        }
    }
    __syncthreads();

    // ---- scores: wave w owns n = w*16 + (l&15); lanes split c into quarters ----
    {
        const int n = w * 16 + (l & 15);
        const int cq = l >> 4;
        float p[8] = {0, 0, 0, 0, 0, 0, 0, 0};
#pragma unroll 4
        for (int c4 = 0; c4 < 16; c4++) {
            const float4 hv = *(const float4*)&hs[n][cq * 64 + c4 * 4];
#pragma unroll
            for (int h = 0; h < 8; h++) {
                const float4 qv = *(const float4*)&qh2[h][cq][c4 * 4];
                p[h] += hv.x * qv.x + hv.y * qv.y + hv.z * qv.z + hv.w * qv.w;
            }
        }
#pragma unroll
        for (int h = 0; h < 8; h++) {
            p[h] += __shfl_xor(p[h], 16, 64);
            p[h] += __shfl_xor(p[h], 32, 64);
        }
        if (cq == 0) {
            const float dv = dist_l[n];
            const int mv = mask_l[n];
#pragma unroll
            for (int h = 0; h < 8; h++) {
                const float s = p[h] * INV_SQRT_HD + kon_l[h] - b1_l[h] * dv;
                sc4[n][h] = mv ? s : -1e30f;
            }
        }
    }
    __syncthreads();

    // ---- softmax over n per head: wave w handles h = 2w + l/32 ----
    {
        const int h = 2 * w + (l >> 5);
        const int n0 = l & 31;
        const float v0 = sc4[n0][h], v1 = sc4[n0 + 32][h];
        float m = fmaxf(v0, v1);
#pragma unroll
        for (int s = 1; s < 32; s <<= 1) m = fmaxf(m, __shfl_xor(m, s, 64));
        const float e0 = __expf(v0 - m), e1 = __expf(v1 - m);
        float sum = e0 + e1;
#pragma unroll
        for (int s = 1; s < 32; s <<= 1) sum += __shfl_xor(sum, s, 64);
        const float inv = 1.0f / sum;
        sc4[n0][h] = e0 * inv;
        sc4[n0 + 32][h] = e1 * inv;
    }
    __syncthreads();

    // ---- attn out: sc4 is exactly [n][h] -> linear copy ----
    {
        const float* sl = &sc4[0][0];
        attn_out[(size_t)b * 512 + t] = sl[t];
        attn_out[(size_t)b * 512 + t + 256] = sl[t + 256];
    }

    // ---- ctx: thread owns column c for ALL 8 heads (hs read once per n) ----
    float acc[8] = {0, 0, 0, 0, 0, 0, 0, 0};
    {
        const int c = t;
        for (int n = 0; n < 64; n += 2) {
            const float4 a0 = *(const float4*)&sc4[n][0];       // wave-uniform broadcast
            const float4 a1 = *(const float4*)&sc4[n][4];
            const float4 c0 = *(const float4*)&sc4[n + 1][0];
            const float4 c1 = *(const float4*)&sc4[n + 1][4];
            const float h0 = hs[n][c];                           // stride-1 across lanes
            const float h1 = hs[n + 1][c];
            acc[0] += a0.x * h0 + c0.x * h1;
            acc[1] += a0.y * h0 + c0.y * h1;
            acc[2] += a0.z * h0 + c0.z * h1;
            acc[3] += a0.w * h0 + c0.w * h1;
            acc[4] += a1.x * h0 + c1.x * h1;
            acc[5] += a1.y * h0 + c1.y * h1;
            acc[6] += a1.z * h0 + c1.z * h1;
            acc[7] += a1.w * h0 + c1.w * h1;
        }
    }
    // stash ctx into qh2 buffer (done being read since pre-softmax sync)
    {
        float* cl = &qh2[0][0][0];                               // view as [8][272]
#pragma unroll
        for (int h = 0; h < 8; h++) cl[h * 272 + t] = acc[h];
    }
    __syncthreads();

    // ---- z = ctx @ wv + wv_b; thread t owns output column j = t ----
    {
        const int j = t;
        const float* cl = &qh2[0][0][0] + (j >> 5) * 272;
        float accz = wv_b[j];
        for (int c4 = 0; c4 < 64; c4++) {
            const float4 cv = *(const float4*)&cl[c4 * 4];       // broadcast per 32-group
            accz += cv.x * wv_w[(c4 * 4 + 0) * 256 + j]
                  + cv.y * wv_w[(c4 * 4 + 1) * 256 + j]
                  + cv.z * wv_w[(c4 * 4 + 2) * 256 + j]
                  + cv.w * wv_w[(c4 * 4 + 3) * 256 + j];
        }
        z_out[(size_t)b * 256 + j] = accz;
    }
}

// ============================ Launch ========================================
extern "C" void kernel_launch(void* const* d_in, const int* in_sizes, int n_in,
                              void* d_out, int out_size, void* d_ws, size_t ws_size,
                              hipStream_t stream)
{
    const float* h_recv = (const float*)d_in[0];
    const float* h_send = (const float*)d_in[1];
    const float* dist   = (const float*)d_in[2];
    const int*   mask   = (const int*)d_in[3];
    const float* wq_w = (const float*)d_in[4];
    const float* wq_b = (const float*)d_in[5];
    const float* wk_w = (const float*)d_in[6];
    const float* wk_b = (const float*)d_in[7];
    const float* wv_w = (const float*)d_in[8];
    const float* wv_b = (const float*)d_in[9];
    const float* d1_w = (const float*)d_in[10];
    const float* d1_b = (const float*)d_in[11];
    const float* d2_w = (const float*)d_in[12];
    const float* d2_b = (const float*)d_in[13];

    float* z_out = (float*)d_out;                              // [B][256]
    float* attn_out = (float*)d_out + (size_t)B_ * HID_;       // [B][64][8]

    float* ws = (float*)d_ws;
    const size_t QH = (size_t)B_ * 8 * 256;                    // 8M floats
    float* qh_ws = ws;
    float* b1_ws = ws + QH;
    float* konst_ws = b1_ws + (size_t)B_ * 8;

    k1_proj<<<512, 256, 0, stream>>>(h_recv, wq_w, wq_b, wk_w, wk_b,
                                     d1_w, d1_b, d2_w, d2_b,
                                     qh_ws, b1_ws, konst_ws);
    k2_attn<<<B_, 256, 0, stream>>>(h_send, dist, mask, qh_ws, b1_ws, konst_ws,
                                    wv_w, wv_b, z_out, attn_out);
}

// Round 3
// 498.232 us; speedup vs baseline: 1.0334x; 1.0334x over previous
//
#include <hip/hip_runtime.h>
#include <math.h>

#define B_   4096
#define N_   64
#define HID_ 256
#define NH_  8
#define HD_  32
#define INV_SQRT_HD 0.17677669529663687f

// ============================ Kernel 1 ======================================
// 1024 blocks x 256 threads; block handles 4 rows of h_recv (4 blocks/CU).
// Outputs: qh_ws[B][8][256], b1_ws[B][8], konst_ws[B][8] (pre-scaled)
__global__ __launch_bounds__(256, 4) void k1_proj(
    const float* __restrict__ h_recv,
    const float* __restrict__ wq_w, const float* __restrict__ wq_b,
    const float* __restrict__ wk_w, const float* __restrict__ wk_b,
    const float* __restrict__ d1_w, const float* __restrict__ d1_b,
    const float* __restrict__ d2_w, const float* __restrict__ d2_b,
    float* __restrict__ qh_ws, float* __restrict__ b1_ws, float* __restrict__ konst_ws)
{
    __shared__ __align__(16) float hr[4][256];
    __shared__ __align__(16) float Q[4][256];
    __shared__ float R1[4][128];
    const int t = threadIdx.x;
    const int brow = blockIdx.x * 4;

    // stage 4 rows of h_recv (256 float4)
    {
        const float4* src = (const float4*)(h_recv + (size_t)brow * 256);
        float4* dst = (float4*)&hr[0][0];
        dst[t] = src[t];
    }
    __syncthreads();

    // Phase A: Q[r][j], j = t
    {
        const int j = t;
        float acc[4];
        const float bq = wq_b[j];
#pragma unroll
        for (int r = 0; r < 4; r++) acc[r] = bq;
#pragma unroll 4
        for (int c4 = 0; c4 < 64; c4++) {
            const float w0 = wq_w[(c4 * 4 + 0) * 256 + j];
            const float w1 = wq_w[(c4 * 4 + 1) * 256 + j];
            const float w2 = wq_w[(c4 * 4 + 2) * 256 + j];
            const float w3 = wq_w[(c4 * 4 + 3) * 256 + j];
#pragma unroll
            for (int r = 0; r < 4; r++) {
                const float4 h = *(const float4*)&hr[r][c4 * 4];
                acc[r] += h.x * w0 + h.y * w1 + h.z * w2 + h.w * w3;
            }
        }
#pragma unroll
        for (int r = 0; r < 4; r++) Q[r][j] = acc[r];
    }
    __syncthreads();

    // Phase B: R1 = relu(h_recv @ d1 + d1_b), rows split 2/2 across thread halves
    {
        const int j = t & 127;
        const int bg = t >> 7;                  // 0..1 -> rows bg*2, bg*2+1
        float acc[2];
        const float bd = d1_b[j];
#pragma unroll
        for (int r = 0; r < 2; r++) acc[r] = bd;
#pragma unroll 4
        for (int c4 = 0; c4 < 64; c4++) {
            const float w0 = d1_w[(c4 * 4 + 0) * 128 + j];
            const float w1 = d1_w[(c4 * 4 + 1) * 128 + j];
            const float w2 = d1_w[(c4 * 4 + 2) * 128 + j];
            const float w3 = d1_w[(c4 * 4 + 3) * 128 + j];
#pragma unroll
            for (int r = 0; r < 2; r++) {
                const float4 h = *(const float4*)&hr[bg * 2 + r][c4 * 4];
                acc[r] += h.x * w0 + h.y * w1 + h.z * w2 + h.w * w3;
            }
        }
#pragma unroll
        for (int r = 0; r < 2; r++) R1[bg * 2 + r][j] = fmaxf(acc[r], 0.0f);
    }
    __syncthreads();

    // Phase C (t<32): softplus MLP head + pre-scaled wk_b constant
    if (t < 32) {
        const int bb = t >> 3, h = t & 7;
        float acc = d2_b[h];
        for (int jj = 0; jj < 128; jj++) acc += R1[bb][jj] * d2_w[jj * 8 + h];
        const float sp = (acc > 20.0f) ? acc : log1pf(expf(acc));
        b1_ws[(size_t)(brow + bb) * 8 + h] = sp;
        float k = 0.0f;
        for (int d = 0; d < 32; d++) k += Q[bb][h * 32 + d] * wk_b[h * 32 + d];
        konst_ws[(size_t)(brow + bb) * 8 + h] = k * INV_SQRT_HD;
    }

    // Phase D: qh[r][h][c] = sum_d Q[r][h*32+d] * wk[c][h*32+d]; c = t
    {
        const int c = t;
        for (int h = 0; h < 8; h++) {
            float acc[4] = {0, 0, 0, 0};
#pragma unroll
            for (int d4 = 0; d4 < 8; d4++) {
                const float4 w = *(const float4*)&wk_w[(size_t)c * 256 + h * 32 + d4 * 4];
#pragma unroll
                for (int r = 0; r < 4; r++) {
                    const float4 q = *(const float4*)&Q[r][h * 32 + d4 * 4];
                    acc[r] += q.x * w.x + q.y * w.y + q.z * w.z + q.w * w.w;
                }
            }
#pragma unroll
            for (int r = 0; r < 4; r++)
                qh_ws[((size_t)(brow + r) * 8 + h) * 256 + c] = acc[r];
        }
    }
}

// ============================ Kernel 2 (fused attn + z) =====================
// One block (256 thr) per batch element. LDS ~11 KB; VGPR-capped for 6 blocks/CU.
// h_send is NOT staged in LDS: scores read it from HBM (full-line consumption),
// ctx re-reads it coalesced from L2.
__global__ __launch_bounds__(256, 6) void k2_attn(
    const float* __restrict__ h_send,
    const float* __restrict__ dist, const int* __restrict__ mask,
    const float* __restrict__ qh_ws, const float* __restrict__ b1_ws,
    const float* __restrict__ konst_ws,
    const float* __restrict__ wv_w, const float* __restrict__ wv_b,
    float* __restrict__ z_out,             // [B][256]
    float* __restrict__ attn_out)          // [B][64][8]
{
    __shared__ __align__(16) float qh2[8][4][68];   // quarter-padded; reused as ctx [8][272]
    __shared__ __align__(16) float sc4[64][8];      // [n][h] == attn output layout
    __shared__ float dist_l[64];
    __shared__ float b1_l[8], kon_l[8];
    __shared__ int mask_l[64];

    const int t = threadIdx.x;
    const int b = blockIdx.x;
    const int w = t >> 6;
    const int l = t & 63;

    // ---- stage qh (8KB) into quarter-padded layout + small vectors ----
    {
        const float4* qsrc = (const float4*)(qh_ws + (size_t)b * 2048);
#pragma unroll
        for (int k = 0; k < 2; k++) {
            const int e = t + k * 256;                       // float4 index in [8][256]
            const float4 v = qsrc[e];
            const int h = e >> 6;
            const int qq = (e & 63) >> 4;
            const int pos = (e & 15) * 4;
            *(float4*)&qh2[h][qq][pos] = v;
        }
        if (t < 64) {
            dist_l[t] = dist[(size_t)b * 64 + t];
            mask_l[t] = mask[(size_t)b * 64 + t];
        } else if (t < 72) {
            b1_l[t - 64] = b1_ws[(size_t)b * 8 + (t - 64)];
            kon_l[t - 64] = konst_ws[(size_t)b * 8 + (t - 64)];
        }
    }
    __syncthreads();

    // ---- scores from GLOBAL: wave w owns n = w*16 + (l&15); lanes split c quarters
    {
        const int n = w * 16 + (l & 15);
        const int cq = l >> 4;
        const float* hrow = h_send + (size_t)b * 16384 + n * 256 + cq * 64;
        float p[8] = {0, 0, 0, 0, 0, 0, 0, 0};
#pragma unroll 4
        for (int c4 = 0; c4 < 16; c4++) {
            const float4 hv = *(const float4*)&hrow[c4 * 4];
#pragma unroll
            for (int h = 0; h < 8; h++) {
                const float4 qv = *(const float4*)&qh2[h][cq][c4 * 4];
                p[h] += hv.x * qv.x + hv.y * qv.y + hv.z * qv.z + hv.w * qv.w;
            }
        }
#pragma unroll
        for (int h = 0; h < 8; h++) {
            p[h] += __shfl_xor(p[h], 16, 64);
            p[h] += __shfl_xor(p[h], 32, 64);
        }
        if (cq == 0) {
            const float dv = dist_l[n];
            const int mv = mask_l[n];
#pragma unroll
            for (int h = 0; h < 8; h++) {
                const float s = p[h] * INV_SQRT_HD + kon_l[h] - b1_l[h] * dv;
                sc4[n][h] = mv ? s : -1e30f;
            }
        }
    }
    __syncthreads();

    // ---- softmax over n per head: wave w handles h = 2w + l/32 ----
    {
        const int h = 2 * w + (l >> 5);
        const int n0 = l & 31;
        const float v0 = sc4[n0][h], v1 = sc4[n0 + 32][h];
        float m = fmaxf(v0, v1);
#pragma unroll
        for (int s = 1; s < 32; s <<= 1) m = fmaxf(m, __shfl_xor(m, s, 64));
        const float e0 = __expf(v0 - m), e1 = __expf(v1 - m);
        float sum = e0 + e1;
#pragma unroll
        for (int s = 1; s < 32; s <<= 1) sum += __shfl_xor(sum, s, 64);
        const float inv = 1.0f / sum;
        sc4[n0][h] = e0 * inv;
        sc4[n0 + 32][h] = e1 * inv;
    }
    __syncthreads();

    // ---- attn out: sc4 is exactly [n][h] -> linear copy ----
    {
        const float* sl = &sc4[0][0];
        attn_out[(size_t)b * 512 + t] = sl[t];
        attn_out[(size_t)b * 512 + t + 256] = sl[t + 256];
    }

    // ---- ctx: thread owns column c=t for ALL 8 heads; h_send re-read from L2,
    //      per-wave 256B contiguous scalar loads ----
    float acc[8] = {0, 0, 0, 0, 0, 0, 0, 0};
    {
        const float* hcol = h_send + (size_t)b * 16384 + t;
        for (int n = 0; n < 64; n += 2) {
            const float4 a0 = *(const float4*)&sc4[n][0];       // wave-uniform broadcast
            const float4 a1 = *(const float4*)&sc4[n][4];
            const float4 c0 = *(const float4*)&sc4[n + 1][0];
            const float4 c1 = *(const float4*)&sc4[n + 1][4];
            const float h0 = hcol[n * 256];
            const float h1 = hcol[n * 256 + 256];
            acc[0] += a0.x * h0 + c0.x * h1;
            acc[1] += a0.y * h0 + c0.y * h1;
            acc[2] += a0.z * h0 + c0.z * h1;
            acc[3] += a0.w * h0 + c0.w * h1;
            acc[4] += a1.x * h0 + c1.x * h1;
            acc[5] += a1.y * h0 + c1.y * h1;
            acc[6] += a1.z * h0 + c1.z * h1;
            acc[7] += a1.w * h0 + c1.w * h1;
        }
    }
    // stash ctx into qh2 buffer (qh reads finished before the softmax syncs)
    {
        float* cl = &qh2[0][0][0];                               // view as [8][272]
#pragma unroll
        for (int h = 0; h < 8; h++) cl[h * 272 + t] = acc[h];
    }
    __syncthreads();

    // ---- z = ctx @ wv + wv_b; thread t owns output column j = t ----
    {
        const int j = t;
        const float* cl = &qh2[0][0][0] + (j >> 5) * 272;
        float accz = wv_b[j];
#pragma unroll 4
        for (int c4 = 0; c4 < 64; c4++) {
            const float4 cv = *(const float4*)&cl[c4 * 4];       // broadcast per 32-group
            accz += cv.x * wv_w[(c4 * 4 + 0) * 256 + j]
                  + cv.y * wv_w[(c4 * 4 + 1) * 256 + j]
                  + cv.z * wv_w[(c4 * 4 + 2) * 256 + j]
                  + cv.w * wv_w[(c4 * 4 + 3) * 256 + j];
        }
        z_out[(size_t)b * 256 + j] = accz;
    }
}

// ============================ Launch ========================================
extern "C" void kernel_launch(void* const* d_in, const int* in_sizes, int n_in,
                              void* d_out, int out_size, void* d_ws, size_t ws_size,
                              hipStream_t stream)
{
    const float* h_recv = (const float*)d_in[0];
    const float* h_send = (const float*)d_in[1];
    const float* dist   = (const float*)d_in[2];
    const int*   mask   = (const int*)d_in[3];
    const float* wq_w = (const float*)d_in[4];
    const float* wq_b = (const float*)d_in[5];
    const float* wk_w = (const float*)d_in[6];
    const float* wk_b = (const float*)d_in[7];
    const float* wv_w = (const float*)d_in[8];
    const float* wv_b = (const float*)d_in[9];
    const float* d1_w = (const float*)d_in[10];
    const float* d1_b = (const float*)d_in[11];
    const float* d2_w = (const float*)d_in[12];
    const float* d2_b = (const float*)d_in[13];

    float* z_out = (float*)d_out;                              // [B][256]
    float* attn_out = (float*)d_out + (size_t)B_ * HID_;       // [B][64][8]

    float* ws = (float*)d_ws;
    const size_t QH = (size_t)B_ * 8 * 256;                    // 8M floats
    float* qh_ws = ws;
    float* b1_ws = ws + QH;
    float* konst_ws = b1_ws + (size_t)B_ * 8;

    k1_proj<<<1024, 256, 0, stream>>>(h_recv, wq_w, wq_b, wk_w, wk_b,
                                      d1_w, d1_b, d2_w, d2_b,
                                      qh_ws, b1_ws, konst_ws);
    k2_attn<<<B_, 256, 0, stream>>>(h_send, dist, mask, qh_ws, b1_ws, konst_ws,
                                    wv_w, wv_b, z_out, attn_out);
}